// Round 3
// baseline (327.300 us; speedup 1.0000x reference)
//
#include <hip/hip_runtime.h>
#include <math.h>

// Problem constants (fixed by reference setup_inputs)
#define BB 32
#define TT 512
#define DD 384
#define NT_BLOCK 64    // o-rows per block = 2 waves x 32
#define R2PI_INV 0.3989422804014327f

typedef short bf16x8 __attribute__((ext_vector_type(8)));
typedef float f32x4  __attribute__((ext_vector_type(4)));

__device__ __forceinline__ ushort f2bf(float f) {
    // round-to-nearest-even fp32 -> bf16
    unsigned u = __float_as_uint(f);
    u += 0x7fffu + ((u >> 16) & 1u);
    return (ushort)(u >> 16);
}

// ---- Kernel 1: feats [B][T][D] fp32 -> featsT [B][D][T] bf16 (vectorized) ----
__global__ __launch_bounds__(256)
void transpose_kernel(const float* __restrict__ feats, ushort* __restrict__ featsT)
{
    __shared__ unsigned sT[64 * 33];  // [t][d-pair], 33-dword row (pad -> no conflicts)
    const int tid = threadIdx.x;
    const int t0 = blockIdx.x * 64, d0 = blockIdx.y * 64, b = blockIdx.z;

    const float4* src = (const float4*)(feats + ((size_t)b * TT + t0) * DD + d0);
    #pragma unroll
    for (int it = 0; it < 4; ++it) {
        int idx = it * 256 + tid;
        int t = idx >> 4, fq = idx & 15;         // 16 float4 per t-row
        float4 v = src[(size_t)t * (DD / 4) + fq];
        sT[t * 33 + 2 * fq]     = (unsigned)f2bf(v.x) | ((unsigned)f2bf(v.y) << 16);
        sT[t * 33 + 2 * fq + 1] = (unsigned)f2bf(v.z) | ((unsigned)f2bf(v.w) << 16);
    }
    __syncthreads();
    const ushort* sU = (const ushort*)sT;        // u16 row stride = 66
    #pragma unroll
    for (int it = 0; it < 2; ++it) {
        int idx = it * 256 + tid;
        int d = idx >> 3, tk = idx & 7;          // 8 threads per d-row, 8 tokens each
        unsigned r[8];
        #pragma unroll
        for (int i = 0; i < 8; ++i) r[i] = sU[(8 * tk + i) * 66 + d];
        uint4 pk;
        pk.x = r[0] | (r[1] << 16);
        pk.y = r[2] | (r[3] << 16);
        pk.z = r[4] | (r[5] << 16);
        pk.w = r[6] | (r[7] << 16);
        *(uint4*)(featsT + ((size_t)(b * DD + d0 + d)) * TT + t0 + 8 * tk) = pk;
    }
}

// ---- Kernel 2: scan + register-resident W (B-frags) + MFMA, A direct from L2 ----
__global__ __launch_bounds__(128, 2)
void gemm_kernel(const ushort* __restrict__ featsT,
                 const float*  __restrict__ rng,
                 const int*    __restrict__ dur,
                 float* __restrict__ out, int O)
{
    __shared__ float sC[TT];
    __shared__ float sIr[TT];
    __shared__ int   sWtot[2];

    const int tid = threadIdx.x;
    const int ln  = tid & 63, wv = tid >> 6;
    const int qd  = ln >> 4,  lm = ln & 15;
    const int b   = blockIdx.y;
    const int o0  = blockIdx.x * NT_BLOCK + wv * 32;   // this wave's first o-row

    // ---- Phase 0: duration scan -> centers, 1/r (per-block, cheap) ----
    int4  dv = ((const int4*)(dur + b * TT))[tid];
    float4 rv = ((const float4*)(rng + b * TT))[tid];
    int s = dv.x + dv.y + dv.z + dv.w;
    int p = s;
    #pragma unroll
    for (int off = 1; off < 64; off <<= 1) {
        int n = __shfl_up(p, off);
        if (ln >= off) p += n;
    }
    if (ln == 63) sWtot[wv] = p;
    __syncthreads();
    {
        int base = (wv == 1) ? sWtot[0] : 0;
        int excl = base + p - s;
        int c1 = excl + dv.x, c2 = c1 + dv.y, c3 = c2 + dv.z, c4 = c3 + dv.w;
        float4 cv = {0.5f * dv.x + (float)c1, 0.5f * dv.y + (float)c2,
                     0.5f * dv.z + (float)c3, 0.5f * dv.w + (float)c4};
        ((float4*)sC)[tid] = cv;
        float4 iv = {1.0f / (rv.x + 1e-6f), 1.0f / (rv.y + 1e-6f),
                     1.0f / (rv.z + 1e-6f), 1.0f / (rv.w + 1e-6f)};
        ((float4*)sIr)[tid] = iv;
    }
    __syncthreads();

    // ---- Phase 1: generate W directly in B-fragment registers ----
    // B[k=qd*8+j][n=lm]: lane (qd,lm) holds w(o=o0+g*16+lm, token=ks*32+qd*8+j)
    bf16x8 W[2][16];
    float sum0 = 0.0f, sum1 = 0.0f;
    const float t_o0 = (float)(o0 + lm);
    const float t_o1 = (float)(o0 + 16 + lm);
    #pragma unroll
    for (int ks = 0; ks < 16; ++ks) {
        const float4* cp = (const float4*)&sC[ks * 32 + qd * 8];
        const float4* ip = (const float4*)&sIr[ks * 32 + qd * 8];
        float4 ca = cp[0], cb = cp[1];
        float4 ia = ip[0], ib = ip[1];
        float c8[8] = {ca.x, ca.y, ca.z, ca.w, cb.x, cb.y, cb.z, cb.w};
        float i8[8] = {ia.x, ia.y, ia.z, ia.w, ib.x, ib.y, ib.z, ib.w};
        ushort h0[8], h1[8];
        #pragma unroll
        for (int j = 0; j < 8; ++j) {
            float z0 = (t_o0 - c8[j]) * i8[j];
            float w0 = __expf(-0.5f * z0 * z0) * i8[j] * R2PI_INV + 1e-6f;
            sum0 += w0; h0[j] = f2bf(w0);
            float z1 = (t_o1 - c8[j]) * i8[j];
            float w1 = __expf(-0.5f * z1 * z1) * i8[j] * R2PI_INV + 1e-6f;
            sum1 += w1; h1[j] = f2bf(w1);
        }
        W[0][ks] = (bf16x8){(short)h0[0], (short)h0[1], (short)h0[2], (short)h0[3],
                            (short)h0[4], (short)h0[5], (short)h0[6], (short)h0[7]};
        W[1][ks] = (bf16x8){(short)h1[0], (short)h1[1], (short)h1[2], (short)h1[3],
                            (short)h1[4], (short)h1[5], (short)h1[6], (short)h1[7]};
    }
    // row sums live across qd-groups: reduce lanes lm, lm+16, lm+32, lm+48
    sum0 += __shfl_xor(sum0, 16); sum0 += __shfl_xor(sum0, 32);
    sum1 += __shfl_xor(sum1, 16); sum1 += __shfl_xor(sum1, 32);
    const float sc0 = 1.0f / sum0;
    const float sc1 = 1.0f / sum1;

    // ---- Phase 2: m-sweep; A-frags straight from featsT (L2-resident) ----
    const ushort* ap = featsT + ((size_t)(b * DD) + lm) * TT + qd * 8;
    const bool st0 = (o0 + lm) < O;
    const bool st1 = (o0 + 16 + lm) < O;
    float* outp0 = out + ((size_t)b * O + (o0 + lm)) * DD + qd * 4;
    float* outp1 = out + ((size_t)b * O + (o0 + 16 + lm)) * DD + qd * 4;

    for (int mt = 0; mt < DD / 16; ++mt) {
        const ushort* a = ap + (size_t)mt * 16 * TT;
        f32x4 acc0 = {0.f, 0.f, 0.f, 0.f};
        f32x4 acc1 = {0.f, 0.f, 0.f, 0.f};
        bf16x8 A[8];
        #pragma unroll
        for (int ks = 0; ks < 8; ++ks) A[ks] = *(const bf16x8*)(a + ks * 32);
        #pragma unroll
        for (int ks = 0; ks < 8; ++ks) {
            acc0 = __builtin_amdgcn_mfma_f32_16x16x32_bf16(A[ks], W[0][ks], acc0, 0, 0, 0);
            acc1 = __builtin_amdgcn_mfma_f32_16x16x32_bf16(A[ks], W[1][ks], acc1, 0, 0, 0);
        }
        #pragma unroll
        for (int ks = 0; ks < 8; ++ks) A[ks] = *(const bf16x8*)(a + (8 + ks) * 32);
        #pragma unroll
        for (int ks = 0; ks < 8; ++ks) {
            acc0 = __builtin_amdgcn_mfma_f32_16x16x32_bf16(A[ks], W[0][8 + ks], acc0, 0, 0, 0);
            acc1 = __builtin_amdgcn_mfma_f32_16x16x32_bf16(A[ks], W[1][8 + ks], acc1, 0, 0, 0);
        }
        // C/D: col=lm -> o, row=qd*4+reg -> d = mt*16 + qd*4 + reg
        if (st0) {
            float4 o4 = {acc0[0] * sc0, acc0[1] * sc0, acc0[2] * sc0, acc0[3] * sc0};
            *(float4*)(outp0 + mt * 16) = o4;
        }
        if (st1) {
            float4 o4 = {acc1[0] * sc1, acc1[1] * sc1, acc1[2] * sc1, acc1[3] * sc1};
            *(float4*)(outp1 + mt * 16) = o4;
        }
    }
}

extern "C" void kernel_launch(void* const* d_in, const int* in_sizes, int n_in,
                              void* d_out, int out_size, void* d_ws, size_t ws_size,
                              hipStream_t stream) {
    const float* feats = (const float*)d_in[0];
    const float* rng   = (const float*)d_in[1];
    const int*   dur   = (const int*)d_in[2];
    float* out = (float*)d_out;
    const int O = out_size / (BB * DD);

    ushort* featsT = (ushort*)d_ws;   // [B][D][T] bf16 = 12.6 MB

    dim3 tg(TT / 64, DD / 64, BB);
    transpose_kernel<<<tg, 256, 0, stream>>>(feats, featsT);
    dim3 gg((O + NT_BLOCK - 1) / NT_BLOCK, BB);
    gemm_kernel<<<gg, 128, 0, stream>>>(featsT, rng, dur, out, O);
}

// Round 4
// 212.017 us; speedup vs baseline: 1.5437x; 1.5437x over previous
//
#include <hip/hip_runtime.h>
#include <math.h>

// Problem constants (fixed by reference setup_inputs)
#define BB 32
#define TT 512
#define DD 384
#define ROWS 48          // output rows per gemm block
#define TW 520           // sW row stride in bf16 elems (1040 B)
#define R2PI_INV 0.3989422804014327f

typedef short bf16x8 __attribute__((ext_vector_type(8)));
typedef float f32x4  __attribute__((ext_vector_type(4)));

__device__ __forceinline__ ushort f2bf(float f) {
    unsigned u = __float_as_uint(f);
    u += 0x7fffu + ((u >> 16) & 1u);
    return (ushort)(u >> 16);
}

// ---- Kernel 1: feats [B][T][D] fp32 -> featsT [B][D][T] bf16;
//      block (0,0,b), wave 0 also computes duration-scan -> centers + 1/r ----
__global__ __launch_bounds__(256)
void prep_transpose_kernel(const float* __restrict__ feats,
                           const float* __restrict__ rng,
                           const int*   __restrict__ dur,
                           ushort* __restrict__ featsT,
                           float* __restrict__ cW,
                           float* __restrict__ irW)
{
    __shared__ unsigned sT[64 * 33];  // [t][d-pair], padded rows
    const int tid = threadIdx.x;
    const int t0 = blockIdx.x * 64, d0 = blockIdx.y * 64, b = blockIdx.z;

    // prep: one wave per batch, single-wave shuffle scan (no barriers needed)
    if (blockIdx.x == 0 && blockIdx.y == 0 && tid < 64) {
        const int ln = tid;
        int4   da = ((const int4*)(dur + b * TT))[2 * ln];
        int4   db = ((const int4*)(dur + b * TT))[2 * ln + 1];
        float4 ra = ((const float4*)(rng + b * TT))[2 * ln];
        float4 rb = ((const float4*)(rng + b * TT))[2 * ln + 1];
        int   d8[8] = {da.x, da.y, da.z, da.w, db.x, db.y, db.z, db.w};
        float r8[8] = {ra.x, ra.y, ra.z, ra.w, rb.x, rb.y, rb.z, rb.w};
        int s8 = 0;
        #pragma unroll
        for (int j = 0; j < 8; ++j) s8 += d8[j];
        int p = s8;
        #pragma unroll
        for (int off = 1; off < 64; off <<= 1) {
            int n = __shfl_up(p, off);
            if (ln >= off) p += n;
        }
        int run = p - s8;   // exclusive prefix of this lane's chunk
        float c8[8], i8[8];
        #pragma unroll
        for (int j = 0; j < 8; ++j) {
            run += d8[j];   // inclusive cumsum
            c8[j] = 0.5f * (float)d8[j] + (float)run;
            i8[j] = 1.0f / (r8[j] + 1e-6f);
        }
        float4* cO = (float4*)(cW + b * TT + 8 * ln);
        cO[0] = (float4){c8[0], c8[1], c8[2], c8[3]};
        cO[1] = (float4){c8[4], c8[5], c8[6], c8[7]};
        float4* iO = (float4*)(irW + b * TT + 8 * ln);
        iO[0] = (float4){i8[0], i8[1], i8[2], i8[3]};
        iO[1] = (float4){i8[4], i8[5], i8[6], i8[7]};
    }

    // transpose 64x64 tile
    const float4* src = (const float4*)(feats + ((size_t)b * TT + t0) * DD + d0);
    #pragma unroll
    for (int it = 0; it < 4; ++it) {
        int idx = it * 256 + tid;
        int t = idx >> 4, fq = idx & 15;
        float4 v = src[(size_t)t * (DD / 4) + fq];
        sT[t * 33 + 2 * fq]     = (unsigned)f2bf(v.x) | ((unsigned)f2bf(v.y) << 16);
        sT[t * 33 + 2 * fq + 1] = (unsigned)f2bf(v.z) | ((unsigned)f2bf(v.w) << 16);
    }
    __syncthreads();
    const ushort* sU = (const ushort*)sT;   // u16 row stride = 66
    #pragma unroll
    for (int it = 0; it < 2; ++it) {
        int idx = it * 256 + tid;
        int d = idx >> 3, tk = idx & 7;
        unsigned r[8];
        #pragma unroll
        for (int i = 0; i < 8; ++i) r[i] = sU[(8 * tk + i) * 66 + d];
        uint4 pk;
        pk.x = r[0] | (r[1] << 16);
        pk.y = r[2] | (r[3] << 16);
        pk.z = r[4] | (r[5] << 16);
        pk.w = r[6] | (r[7] << 16);
        *(uint4*)(featsT + ((size_t)(b * DD + d0 + d)) * TT + t0 + 8 * tk) = pk;
    }
}

// ---- Kernel 2: W-in-LDS MFMA GEMM, XCD-local b, depth-2 B prefetch ----
__global__ __launch_bounds__(256)
void gemm_kernel(const ushort* __restrict__ featsT,
                 const float*  __restrict__ cW,
                 const float*  __restrict__ irW,
                 float* __restrict__ out, int O, int OB)
{
    __shared__ ushort sW[ROWS * TW];   // 49,920 B
    __shared__ float  sInvSum[ROWS];

    const int tid = threadIdx.x;
    const int ln  = tid & 63, wv = tid >> 6;
    const int qd  = ln >> 4,  lm = ln & 15;

    // XCD-aware swizzle: each XCD streams one b at a time (featsT slice L2-resident)
    const int id  = blockIdx.x;
    const int xcd = id & 7;
    const int s   = id >> 3;            // 0 .. OB*4-1
    const int b   = (s / OB) * 8 + xcd; // 4 b's per XCD
    const int i0  = (s % OB) * ROWS;

    // ---- Phase 1: W rows (bf16, unnormalized) into LDS + fp32 row sums ----
    float c8[8], i8[8];
    {
        const float4* cB = (const float4*)(cW + b * TT + 8 * ln);
        const float4* iB = (const float4*)(irW + b * TT + 8 * ln);
        float4 ca = cB[0], cb = cB[1];
        float4 ia = iB[0], ib = iB[1];
        c8[0] = ca.x; c8[1] = ca.y; c8[2] = ca.z; c8[3] = ca.w;
        c8[4] = cb.x; c8[5] = cb.y; c8[6] = cb.z; c8[7] = cb.w;
        i8[0] = ia.x; i8[1] = ia.y; i8[2] = ia.z; i8[3] = ia.w;
        i8[4] = ib.x; i8[5] = ib.y; i8[6] = ib.z; i8[7] = ib.w;
    }
    #pragma unroll
    for (int rr = 0; rr < ROWS / 4; ++rr) {      // 12 rows per wave
        int row = wv * (ROWS / 4) + rr;
        float time = (float)(i0 + row);
        float sum = 0.0f;
        ushort h[8];
        #pragma unroll
        for (int j = 0; j < 8; ++j) {
            float z = (time - c8[j]) * i8[j];
            float w = __expf(-0.5f * z * z) * i8[j] * R2PI_INV + 1e-6f;
            sum += w;
            h[j] = f2bf(w);
        }
        uint4 pk;
        pk.x = (unsigned)h[0] | ((unsigned)h[1] << 16);
        pk.y = (unsigned)h[2] | ((unsigned)h[3] << 16);
        pk.z = (unsigned)h[4] | ((unsigned)h[5] << 16);
        pk.w = (unsigned)h[6] | ((unsigned)h[7] << 16);
        *(uint4*)&sW[row * TW + 8 * ln] = pk;
        #pragma unroll
        for (int off = 32; off >= 1; off >>= 1) sum += __shfl_xor(sum, off);
        if (ln == 0) sInvSum[row] = 1.0f / sum;
    }
    __syncthreads();

    // ---- Phase 2: MFMA; waves split N (96 cols each); depth-2 global B prefetch ----
    f32x4 acc[3][6];
    #pragma unroll
    for (int r = 0; r < 3; ++r)
        #pragma unroll
        for (int nt = 0; nt < 6; ++nt)
            acc[r][nt] = (f32x4){0.f, 0.f, 0.f, 0.f};

    const int colbase = wv * 96 + lm;
    const ushort* bp = featsT + ((size_t)(b * DD + colbase)) * TT + qd * 8;

    bf16x8 B0[6], B1[6];
    #pragma unroll
    for (int nt = 0; nt < 6; ++nt) B0[nt] = *(const bf16x8*)(bp + (size_t)nt * 16 * TT);
    #pragma unroll
    for (int nt = 0; nt < 6; ++nt) B1[nt] = *(const bf16x8*)(bp + (size_t)nt * 16 * TT + 32);

    for (int ks = 0; ks < 16; ks += 2) {
        #pragma unroll
        for (int r = 0; r < 3; ++r) {
            bf16x8 A = *(const bf16x8*)&sW[(r * 16 + lm) * TW + ks * 32 + qd * 8];
            #pragma unroll
            for (int nt = 0; nt < 6; ++nt)
                acc[r][nt] = __builtin_amdgcn_mfma_f32_16x16x32_bf16(A, B0[nt], acc[r][nt], 0, 0, 0);
        }
        if (ks + 2 < 16) {
            #pragma unroll
            for (int nt = 0; nt < 6; ++nt)
                B0[nt] = *(const bf16x8*)(bp + (size_t)nt * 16 * TT + (ks + 2) * 32);
        }
        #pragma unroll
        for (int r = 0; r < 3; ++r) {
            bf16x8 A = *(const bf16x8*)&sW[(r * 16 + lm) * TW + (ks + 1) * 32 + qd * 8];
            #pragma unroll
            for (int nt = 0; nt < 6; ++nt)
                acc[r][nt] = __builtin_amdgcn_mfma_f32_16x16x32_bf16(A, B1[nt], acc[r][nt], 0, 0, 0);
        }
        if (ks + 3 < 16) {
            #pragma unroll
            for (int nt = 0; nt < 6; ++nt)
                B1[nt] = *(const bf16x8*)(bp + (size_t)nt * 16 * TT + (ks + 3) * 32);
        }
    }

    // ---- Epilogue: scale by 1/rowsum, store. C/D: col=lm (-> d), row=qd*4+reg (-> o) ----
    #pragma unroll
    for (int r = 0; r < 3; ++r) {
        #pragma unroll
        for (int reg = 0; reg < 4; ++reg) {
            int lrow = r * 16 + qd * 4 + reg;
            int grow = i0 + lrow;
            if (grow < O) {
                float sc = sInvSum[lrow];
                float* op = out + ((size_t)b * O + grow) * DD + wv * 96 + lm;
                #pragma unroll
                for (int nt = 0; nt < 6; ++nt)
                    op[nt * 16] = acc[r][nt][reg] * sc;
            }
        }
    }
}

extern "C" void kernel_launch(void* const* d_in, const int* in_sizes, int n_in,
                              void* d_out, int out_size, void* d_ws, size_t ws_size,
                              hipStream_t stream) {
    const float* feats = (const float*)d_in[0];
    const float* rng   = (const float*)d_in[1];
    const int*   dur   = (const int*)d_in[2];
    float* out = (float*)d_out;
    const int O = out_size / (BB * DD);
    const int OB = (O + ROWS - 1) / ROWS;

    // workspace: featsT bf16 [B][D][T] | centers [B][T] f32 | invr [B][T] f32
    ushort* featsT = (ushort*)d_ws;
    float*  cW  = (float*)((char*)d_ws + (size_t)BB * DD * TT * 2);
    float*  irW = cW + BB * TT;

    dim3 tg(TT / 64, DD / 64, BB);
    prep_transpose_kernel<<<tg, 256, 0, stream>>>(feats, rng, dur, featsT, cW, irW);
    gemm_kernel<<<OB * BB, 256, 0, stream>>>(featsT, cW, irW, out, O, OB);
}